// Round 8
// baseline (283.829 us; speedup 1.0000x reference)
//
#include <hip/hip_runtime.h>
#include <hip/hip_bf16.h>
#include <stdint.h>

typedef float f32x2 __attribute__((ext_vector_type(2)));
typedef float f32x4 __attribute__((ext_vector_type(4)));
typedef short s16x8 __attribute__((ext_vector_type(8)));

#define CUBIC_A (-0.75f)
#define S3 262144.0f   // 2^18 scale for plane3
#define S2 131072.0f   // 2^17 scale for plane2
#define SV 32768.0f    // 2^15 scale for vec

// padded plane geometry (x-axis padded with clamped border texels at both ends)
#define PL3 (128 * 132 * 32)   // per-plane bytes, scale 3 (H=128, Wp=132)
#define PL2 (256 * 260 * 32)   // scale 2 (H=256, Wp=260)
#define PLV (516 * 32)         // vec (Wp=516)
#define STRIDE3 (132 * 32)
#define STRIDE2 (260 * 32)

__device__ __forceinline__ void cubic_w(float t, float* w) {
  float s = t + 1.0f;
  w[0] = ((CUBIC_A * s - 5.0f * CUBIC_A) * s + 8.0f * CUBIC_A) * s - 4.0f * CUBIC_A;
  w[1] = ((CUBIC_A + 2.0f) * t - (CUBIC_A + 3.0f)) * t * t + 1.0f;
  float u = 1.0f - t;
  w[2] = ((CUBIC_A + 2.0f) * u - (CUBIC_A + 3.0f)) * u * u + 1.0f;
  float v = 2.0f - t;
  w[3] = ((CUBIC_A * v - 5.0f * CUBIC_A) * v + 8.0f * CUBIC_A) * v - 4.0f * CUBIC_A;
}

// col-axis: weights + window base byte (padded layout: window start x0-1 -> byte x0*32)
__device__ __forceinline__ void axis_w(float c, int size, float* w, int* colb) {
  float ix = (c + 1.0f) * 0.5f * (float)(size - 1);
  float x0f = floorf(ix);
  cubic_w(ix - x0f, w);
  *colb = (int)x0f * 32;
}

// row-axis: weights + clamped row byte offsets
__device__ __forceinline__ void axis_r(float c, int size, int strideB, float* w, int* ro) {
  float ix = (c + 1.0f) * 0.5f * (float)(size - 1);
  float x0f = floorf(ix);
  cubic_w(ix - x0f, w);
  int x0 = (int)x0f;
#pragma unroll
  for (int k = 0; k < 4; ++k) {
    int qq = x0 - 1 + k;
    qq = qq < 0 ? 0 : qq;
    qq = qq > size - 1 ? size - 1 : qq;
    ro[k] = qq * strideB;
  }
}

// both (y axis is used as rows and cols)
__device__ __forceinline__ void axis_wr(float c, int size, int strideB, float* w, int* colb, int* ro) {
  float ix = (c + 1.0f) * 0.5f * (float)(size - 1);
  float x0f = floorf(ix);
  cubic_w(ix - x0f, w);
  int x0 = (int)x0f;
  *colb = x0 * 32;
#pragma unroll
  for (int k = 0; k < 4; ++k) {
    int qq = x0 - 1 + k;
    qq = qq < 0 ? 0 : qq;
    qq = qq > size - 1 ? size - 1 : qq;
    ro[k] = qq * strideB;
  }
}

// issue 8 x 16B loads: 4 rows x 2 half-windows (lane's q*16 already folded into base)
__device__ __forceinline__ void issueW(const uint8_t* __restrict__ base,
                                       const int* ro, int cb, uint4* r) {
#pragma unroll
  for (int i = 0; i < 4; ++i) {
    r[2 * i]     = *reinterpret_cast<const uint4*>(base + ro[i] + cb);
    r[2 * i + 1] = *reinterpret_cast<const uint4*>(base + ro[i] + cb + 64);
  }
}

// unpack 16 fp8 channels with one weight into acc8 (8 f32x2 = 16 ch)
__device__ __forceinline__ void consume16(uint4 v, float w, f32x2* acc8) {
  f32x2 w2; w2.x = w; w2.y = w;
  acc8[0] += w2 * __builtin_amdgcn_cvt_pk_f32_fp8((int)v.x, false);
  acc8[1] += w2 * __builtin_amdgcn_cvt_pk_f32_fp8((int)v.x, true);
  acc8[2] += w2 * __builtin_amdgcn_cvt_pk_f32_fp8((int)v.y, false);
  acc8[3] += w2 * __builtin_amdgcn_cvt_pk_f32_fp8((int)v.y, true);
  acc8[4] += w2 * __builtin_amdgcn_cvt_pk_f32_fp8((int)v.z, false);
  acc8[5] += w2 * __builtin_amdgcn_cvt_pk_f32_fp8((int)v.z, true);
  acc8[6] += w2 * __builtin_amdgcn_cvt_pk_f32_fp8((int)v.w, false);
  acc8[7] += w2 * __builtin_amdgcn_cvt_pk_f32_fp8((int)v.w, true);
}

// consume one plane sample: 4 rows x {texel p0 (w=wr*cw0), texel p0+2 (w=wr*cw1)}
__device__ __forceinline__ void consumeW(const float* wr, float cw0, float cw1,
                                         const uint4* r, f32x2* acc8) {
#pragma unroll
  for (int i = 0; i < 4; ++i) {
    consume16(r[2 * i],     wr[i] * cw0, acc8);
    consume16(r[2 * i + 1], wr[i] * cw1, acc8);
  }
}

// ---------------- prep kernels ----------------

__device__ __forceinline__ float comb_row(const float* __restrict__ B, int r, int j) {
  return (r < 32) ? (B[r * 64 + j] + B[(r + 32) * 64 + j]) : B[(r + 32) * 64 + j];
}

__device__ __forceinline__ uint32_t pack_bf16(float v0, float v1) {
  uint32_t a = __float_as_uint(v0);
  uint32_t b = __float_as_uint(v1);
  uint32_t r0 = (a + 0x7fffu + ((a >> 16) & 1u)) >> 16;     // RNE
  uint32_t r1 = (b + 0x7fffu + ((b >> 16) & 1u)) >> 16;
  return (r0 & 0xffffu) | (r1 << 16);
}

// Bf[seg=3][cb=4][lane=64] = uint4 (8 bf16, k=(lane>>4)*8+e, j=cb*16+(lane&15)), invS folded
__global__ void __launch_bounds__(256) make_bfrag(const float* __restrict__ B, uint4* __restrict__ Bf) {
  int i = blockIdx.x * 256 + threadIdx.x;
  if (i >= 768) return;
  int lane = i & 63;
  int cb = (i >> 6) & 3;
  int seg = i >> 8;
  float invS = (seg == 0) ? (1.0f / S3) : (seg == 1) ? (1.0f / S2) : (1.0f / SV);
  int j = cb * 16 + (lane & 15);
  int h = lane >> 4;
  uint32_t o[4];
#pragma unroll
  for (int r = 0; r < 4; ++r) {
    int k0 = seg * 32 + h * 8 + 2 * r;
    float v0 = comb_row(B, k0, j) * invS;
    float v1 = comb_row(B, k0 + 1, j) * invS;
    o[r] = pack_bf16(v0, v1);
  }
  uint4 st; st.x = o[0]; st.y = o[1]; st.z = o[2]; st.w = o[3];
  Bf[(seg * 4 + cb) * 64 + lane] = st;
}

// Transpose+quantize (P, 32, H, W) fp32 -> (P, H, Wp, 32) fp8 e4m3 scaled by S,
// with x-padding: texel x stored at slot x+1; slot 0 = texel 0; slots W+1,W+2 = texel W-1.
__global__ void __launch_bounds__(256) transpose_cl8(const float* __restrict__ in,
                                                     uint8_t* __restrict__ out,
                                                     int H, int W, int Wp, int nxt, float S) {
  __shared__ float tile[32][65];
  int b = blockIdx.x;
  int xt = b % nxt;
  int tmp = b / nxt;
  int y = tmp % H;
  int p = tmp / H;
  int x0 = xt * 64;
  int lane = threadIdx.x;
  const float* src = in + ((size_t)p * 32 * (size_t)H) * (size_t)W + (size_t)y * (size_t)W;
  int cx = lane & 63;
  int c4 = lane >> 6;
#pragma unroll
  for (int pass = 0; pass < 8; ++pass) {
    int c = pass * 4 + c4;
    tile[c][cx] = src[(size_t)c * (size_t)(H) * (size_t)W + x0 + cx];
  }
  __syncthreads();
  int xx = lane >> 2;
  int c8 = (lane & 3) * 8;
  float f[8];
#pragma unroll
  for (int i = 0; i < 8; ++i) f[i] = tile[c8 + i][xx] * S;
  uint32_t lo = 0, hi = 0;
  lo = (uint32_t)__builtin_amdgcn_cvt_pk_fp8_f32(f[0], f[1], (int)lo, false);
  lo = (uint32_t)__builtin_amdgcn_cvt_pk_fp8_f32(f[2], f[3], (int)lo, true);
  hi = (uint32_t)__builtin_amdgcn_cvt_pk_fp8_f32(f[4], f[5], (int)hi, false);
  hi = (uint32_t)__builtin_amdgcn_cvt_pk_fp8_f32(f[6], f[7], (int)hi, true);
  uint2 st; st.x = lo; st.y = hi;
  int x = x0 + xx;
  uint8_t* rowb = out + (((size_t)p * H + y) * (size_t)Wp) * 32;
  *reinterpret_cast<uint2*>(rowb + (size_t)(x + 1) * 32 + c8) = st;
  if (x == 0)
    *reinterpret_cast<uint2*>(rowb + c8) = st;
  if (x == W - 1) {
    *reinterpret_cast<uint2*>(rowb + (size_t)(W + 1) * 32 + c8) = st;
    *reinterpret_cast<uint2*>(rowb + (size_t)(W + 2) * 32 + c8) = st;
  }
}

// ---------------- main kernel: window gathers (2x dwordx4 per sample-row), MFMA projection ----------------

__global__ void __launch_bounds__(256, 8) triplane_main(
    const float* __restrict__ coords,
    const uint8_t* __restrict__ p3t,   // (3,128,132,32) fp8, x-padded
    const uint8_t* __restrict__ p2t,   // (3,256,260,32) fp8
    const uint8_t* __restrict__ vt,    // (3,516,32) fp8
    const uint4* __restrict__ Bfrag,   // [3][4][64] uint4
    float* __restrict__ out, int N) {
  int t = blockIdx.x * 256 + threadIdx.x;
  int l = threadIdx.x & 63;
  int n0 = (blockIdx.x * 256 + (threadIdx.x & ~63)) >> 2;  // first point of this wave
  if (n0 >= N) return;
  int n = t >> 2;
  int q = l & 3;
  bool hiq = (q >> 1) != 0;   // texel-pair selector
  int q16 = q * 16;

  float x = coords[3 * n + 0];
  float y = coords[3 * n + 1];
  float z = coords[3 * n + 2];

  f32x2 feat2[24];   // [seg=3][8]: entry e = channels {2e,2e+1} of this lane's 16-ch half
#pragma unroll
  for (int i = 0; i < 24; ++i) { feat2[i].x = 0.f; feat2[i].y = 0.f; }

  uint4 rA[8], rB[8];

  // ======== scale 3 (H=128) ========
  float wx[4], wy[4], wz[4];
  int cbx, cby, roy[4], roz[4];
  axis_w(x, 128, wx, &cbx);
  axis_wr(y, 128, STRIDE3, wy, &cby, roy);
  axis_r(z, 128, STRIDE3, wz, roz);
  float cx0 = hiq ? wx[1] : wx[0], cx1 = hiq ? wx[3] : wx[2];
  float cy0 = hiq ? wy[1] : wy[0], cy1 = hiq ? wy[3] : wy[2];

  const uint8_t* b3 = p3t + q16;
  issueW(b3,           roy, cbx, rA);   // xy: rows y, cols x
  issueW(b3 + 1 * PL3, roz, cby, rB);   // yz: rows z, cols y
  consumeW(wy, cx0, cx1, rA, feat2 + 0);
  issueW(b3 + 2 * PL3, roz, cbx, rA);   // xz: rows z, cols x
  consumeW(wz, cy0, cy1, rB, feat2 + 0);

  // ======== scale 2 (H=256) ========
  float wx2[4], wy2[4], wz2[4];
  int cbx2, cby2, roy2[4], roz2[4];
  axis_w(x, 256, wx2, &cbx2);
  axis_wr(y, 256, STRIDE2, wy2, &cby2, roy2);
  axis_r(z, 256, STRIDE2, wz2, roz2);
  float cx20 = hiq ? wx2[1] : wx2[0], cx21 = hiq ? wx2[3] : wx2[2];
  float cy20 = hiq ? wy2[1] : wy2[0], cy21 = hiq ? wy2[3] : wy2[2];

  const uint8_t* b2 = p2t + q16;
  issueW(b2,           roy2, cbx2, rB);               // p2 xy
  consumeW(wz, cx0, cx1, rA, feat2 + 0);              // p3 xz
  issueW(b2 + 1 * PL2, roz2, cby2, rA);               // p2 yz
  consumeW(wy2, cx20, cx21, rB, feat2 + 8);           // p2 xy
  issueW(b2 + 2 * PL2, roz2, cbx2, rB);               // p2 xz
  consumeW(wz2, cy20, cy21, rA, feat2 + 8);           // p2 yz

  // ======== vector (W=512) ========
  float wvx[4], wvy[4], wvz[4];
  int cbvx, cbvy, cbvz;
  axis_w(x, 512, wvx, &cbvx);
  axis_w(y, 512, wvy, &cbvy);
  axis_w(z, 512, wvz, &cbvz);
  {
    const uint8_t* v0 = vt + q16;
    rA[0] = *reinterpret_cast<const uint4*>(v0 + cbvx);
    rA[1] = *reinterpret_cast<const uint4*>(v0 + cbvx + 64);
    rA[2] = *reinterpret_cast<const uint4*>(v0 + PLV + cbvy);
    rA[3] = *reinterpret_cast<const uint4*>(v0 + PLV + cbvy + 64);
    rA[4] = *reinterpret_cast<const uint4*>(v0 + 2 * PLV + cbvz);
    rA[5] = *reinterpret_cast<const uint4*>(v0 + 2 * PLV + cbvz + 64);
  }
  consumeW(wz2, cx20, cx21, rB, feat2 + 8);           // p2 xz
  {
    float a0 = hiq ? wvx[1] : wvx[0], a1 = hiq ? wvx[3] : wvx[2];
    float b0 = hiq ? wvy[1] : wvy[0], b1 = hiq ? wvy[3] : wvy[2];
    float c0 = hiq ? wvz[1] : wvz[0], c1 = hiq ? wvz[3] : wvz[2];
    consume16(rA[0], a0, feat2 + 16);
    consume16(rA[1], a1, feat2 + 16);
    consume16(rA[2], b0, feat2 + 16);
    consume16(rA[3], b1, feat2 + 16);
    consume16(rA[4], c0, feat2 + 16);
    consume16(rA[5], c1, feat2 + 16);
  }

  // ---- pair-reduce (lane q with lane q^2) + pack own k-quarter to bf16 ----
  // lane q owns quarter qq = ((q&1)<<1)|(q>>1): half q&1, channel offset 8*(q>>1)
  uint32_t packed[12];
#pragma unroll
  for (int s = 0; s < 3; ++s) {
#pragma unroll
    for (int r = 0; r < 4; ++r) {
      f32x2 lo = feat2[s * 8 + r];
      f32x2 hi = feat2[s * 8 + 4 + r];
      float ownx = hiq ? hi.x : lo.x, owny = hiq ? hi.y : lo.y;
      float sndx = hiq ? lo.x : hi.x, sndy = hiq ? lo.y : hi.y;
      float rx = ownx + __shfl_xor(sndx, 2);
      float ry = owny + __shfl_xor(sndy, 2);
      uint32_t pk;
      asm("v_cvt_pk_bf16_f32 %0, %1, %2" : "=v"(pk) : "v"(rx), "v"(ry));
      packed[s * 4 + r] = pk;
    }
  }

  // ---- redistribute to MFMA A-fragment: dest lane 16h'+p pulls quarter h' of point p.
  // quarter h' lives in lane 4p + ((h'&1)<<1 | h'>>1)
  int hp = l >> 4;
  int srcq = ((hp & 1) << 1) | (hp >> 1);
  int baddr = (4 * (l & 15) + srcq) * 4;
  uint32_t apk[12];
#pragma unroll
  for (int i = 0; i < 12; ++i)
    apk[i] = (uint32_t)__builtin_amdgcn_ds_bpermute(baddr, (int)packed[i]);

  // ---- load B fragments ----
  uint4 bfr[12];
#pragma unroll
  for (int i = 0; i < 12; ++i) bfr[i] = Bfrag[i * 64 + l];

  // ---- 12 MFMAs ----
  union U { uint32_t u[4]; s16x8 v; };
  f32x4 acc[4];
#pragma unroll
  for (int cb = 0; cb < 4; ++cb) { acc[cb].x = 0.f; acc[cb].y = 0.f; acc[cb].z = 0.f; acc[cb].w = 0.f; }
#pragma unroll
  for (int seg = 0; seg < 3; ++seg) {
    U a;
    a.u[0] = apk[seg * 4 + 0];
    a.u[1] = apk[seg * 4 + 1];
    a.u[2] = apk[seg * 4 + 2];
    a.u[3] = apk[seg * 4 + 3];
#pragma unroll
    for (int cb = 0; cb < 4; ++cb) {
      U b;
      b.u[0] = bfr[seg * 4 + cb].x;
      b.u[1] = bfr[seg * 4 + cb].y;
      b.u[2] = bfr[seg * 4 + cb].z;
      b.u[3] = bfr[seg * 4 + cb].w;
      acc[cb] = __builtin_amdgcn_mfma_f32_16x16x32_bf16(a.v, b.v, acc[cb], 0, 0, 0);
    }
  }

  // ---- epilogue: sin/cos + store. C/D: row (=point) = (l>>4)*4+reg, col = l&15 ----
  int jc = l & 15;
#pragma unroll
  for (int cb = 0; cb < 4; ++cb) {
#pragma unroll
    for (int reg = 0; reg < 4; ++reg) {
      float v = acc[cb][reg];
      float sv = __builtin_amdgcn_sinf(v);   // reference is sin(2*pi*dot); v_sin takes revolutions
      float cv = __builtin_amdgcn_cosf(v);
      float* po = out + (size_t)(n0 + 4 * hp + reg) * 128 + cb * 16 + jc;
      po[0] = sv;
      po[64] = cv;
    }
  }
}

// ---------------- launcher ----------------

extern "C" void kernel_launch(void* const* d_in, const int* in_sizes, int n_in,
                              void* d_out, int out_size, void* d_ws, size_t ws_size,
                              hipStream_t stream) {
  const float* coords = (const float*)d_in[0];
  const float* plane3 = (const float*)d_in[1];
  const float* plane2 = (const float*)d_in[2];
  const float* vec1   = (const float*)d_in[3];
  const float* B      = (const float*)d_in[4];
  float* out = (float*)d_out;
  int N = in_sizes[0] / 3;

  char* ws = (char*)d_ws;
  const size_t off_p3 = 0;
  const size_t off_p2 = off_p3 + (size_t)3 * PL3;   // 1,622,016
  const size_t off_vt = off_p2 + (size_t)3 * PL2;   // +6,389,760
  const size_t off_bf = off_vt + (size_t)3 * PLV;   // +49,536
  uint8_t* p3t = (uint8_t*)(ws + off_p3);
  uint8_t* p2t = (uint8_t*)(ws + off_p2);
  uint8_t* vt  = (uint8_t*)(ws + off_vt);
  uint4* Bf = (uint4*)(ws + off_bf);

  hipLaunchKernelGGL(make_bfrag, dim3(3), dim3(256), 0, stream, B, Bf);
  hipLaunchKernelGGL(transpose_cl8, dim3(3 * 128 * 2), dim3(256), 0, stream, plane3, p3t, 128, 128, 132, 2, S3);
  hipLaunchKernelGGL(transpose_cl8, dim3(3 * 256 * 4), dim3(256), 0, stream, plane2, p2t, 256, 256, 260, 4, S2);
  hipLaunchKernelGGL(transpose_cl8, dim3(3 * 1 * 8), dim3(256), 0, stream, vec1, vt, 1, 512, 516, 8, SV);
  hipLaunchKernelGGL(triplane_main, dim3((N * 4 + 255) / 256), dim3(256), 0, stream,
                     coords, p3t, p2t, vt, Bf, out, N);
}

// Round 9
// 196.632 us; speedup vs baseline: 1.4435x; 1.4435x over previous
//
#include <hip/hip_runtime.h>
#include <hip/hip_bf16.h>
#include <stdint.h>

typedef float f32x2 __attribute__((ext_vector_type(2)));
typedef float f32x4 __attribute__((ext_vector_type(4)));
typedef short s16x8 __attribute__((ext_vector_type(8)));

#define CUBIC_A (-0.75f)
#define S3 262144.0f   // 2^18 scale for plane3
#define S2 131072.0f   // 2^17 scale for plane2
#define SV 32768.0f    // 2^15 scale for vec

// padded plane geometry (x-axis padded with clamped border texels at both ends)
#define PL3 (128 * 132 * 32)   // per-plane bytes, scale 3 (H=128, Wp=132)
#define PL2 (256 * 260 * 32)   // scale 2 (H=256, Wp=260)
#define PLV (516 * 32)         // vec (Wp=516)
#define STRIDE3 (132 * 32)
#define STRIDE2 (260 * 32)

#define NBINS 32768            // 5 bits per axis

__device__ __forceinline__ void cubic_w(float t, float* w) {
  float s = t + 1.0f;
  w[0] = ((CUBIC_A * s - 5.0f * CUBIC_A) * s + 8.0f * CUBIC_A) * s - 4.0f * CUBIC_A;
  w[1] = ((CUBIC_A + 2.0f) * t - (CUBIC_A + 3.0f)) * t * t + 1.0f;
  float u = 1.0f - t;
  w[2] = ((CUBIC_A + 2.0f) * u - (CUBIC_A + 3.0f)) * u * u + 1.0f;
  float v = 2.0f - t;
  w[3] = ((CUBIC_A * v - 5.0f * CUBIC_A) * v + 8.0f * CUBIC_A) * v - 4.0f * CUBIC_A;
}

// col-axis: weights + window base byte (padded layout: window start x0-1 -> byte x0*32)
__device__ __forceinline__ void axis_w(float c, int size, float* w, int* colb) {
  float ix = (c + 1.0f) * 0.5f * (float)(size - 1);
  float x0f = floorf(ix);
  cubic_w(ix - x0f, w);
  *colb = (int)x0f * 32;
}

// row-axis: weights + clamped row byte offsets
__device__ __forceinline__ void axis_r(float c, int size, int strideB, float* w, int* ro) {
  float ix = (c + 1.0f) * 0.5f * (float)(size - 1);
  float x0f = floorf(ix);
  cubic_w(ix - x0f, w);
  int x0 = (int)x0f;
#pragma unroll
  for (int k = 0; k < 4; ++k) {
    int qq = x0 - 1 + k;
    qq = qq < 0 ? 0 : qq;
    qq = qq > size - 1 ? size - 1 : qq;
    ro[k] = qq * strideB;
  }
}

// both (y axis is used as rows and cols)
__device__ __forceinline__ void axis_wr(float c, int size, int strideB, float* w, int* colb, int* ro) {
  float ix = (c + 1.0f) * 0.5f * (float)(size - 1);
  float x0f = floorf(ix);
  cubic_w(ix - x0f, w);
  int x0 = (int)x0f;
  *colb = x0 * 32;
#pragma unroll
  for (int k = 0; k < 4; ++k) {
    int qq = x0 - 1 + k;
    qq = qq < 0 ? 0 : qq;
    qq = qq > size - 1 ? size - 1 : qq;
    ro[k] = qq * strideB;
  }
}

// issue 8 x 16B loads: 4 rows x 2 half-windows (lane's q*16 already folded into base)
__device__ __forceinline__ void issueW(const uint8_t* __restrict__ base,
                                       const int* ro, int cb, uint4* r) {
#pragma unroll
  for (int i = 0; i < 4; ++i) {
    r[2 * i]     = *reinterpret_cast<const uint4*>(base + ro[i] + cb);
    r[2 * i + 1] = *reinterpret_cast<const uint4*>(base + ro[i] + cb + 64);
  }
}

// unpack 16 fp8 channels with one weight into acc8 (8 f32x2 = 16 ch)
__device__ __forceinline__ void consume16(uint4 v, float w, f32x2* acc8) {
  f32x2 w2; w2.x = w; w2.y = w;
  acc8[0] += w2 * __builtin_amdgcn_cvt_pk_f32_fp8((int)v.x, false);
  acc8[1] += w2 * __builtin_amdgcn_cvt_pk_f32_fp8((int)v.x, true);
  acc8[2] += w2 * __builtin_amdgcn_cvt_pk_f32_fp8((int)v.y, false);
  acc8[3] += w2 * __builtin_amdgcn_cvt_pk_f32_fp8((int)v.y, true);
  acc8[4] += w2 * __builtin_amdgcn_cvt_pk_f32_fp8((int)v.z, false);
  acc8[5] += w2 * __builtin_amdgcn_cvt_pk_f32_fp8((int)v.z, true);
  acc8[6] += w2 * __builtin_amdgcn_cvt_pk_f32_fp8((int)v.w, false);
  acc8[7] += w2 * __builtin_amdgcn_cvt_pk_f32_fp8((int)v.w, true);
}

// consume one plane sample: 4 rows x {texel p0 (w=wr*cw0), texel p0+2 (w=wr*cw1)}
__device__ __forceinline__ void consumeW(const float* wr, float cw0, float cw1,
                                         const uint4* r, f32x2* acc8) {
#pragma unroll
  for (int i = 0; i < 4; ++i) {
    consume16(r[2 * i],     wr[i] * cw0, acc8);
    consume16(r[2 * i + 1], wr[i] * cw1, acc8);
  }
}

// ---------------- sort kernels ----------------

__device__ __forceinline__ int bin_of(float x, float y, float z) {
  int bx = (int)((x + 1.0f) * 16.0f); bx = bx < 0 ? 0 : (bx > 31 ? 31 : bx);
  int by = (int)((y + 1.0f) * 16.0f); by = by < 0 ? 0 : (by > 31 ? 31 : by);
  int bz = (int)((z + 1.0f) * 16.0f); bz = bz < 0 ? 0 : (bz > 31 ? 31 : bz);
  return (bz << 10) | (by << 5) | bx;   // x fastest
}

__global__ void __launch_bounds__(256) zero_hist(uint32_t* __restrict__ hist) {
  int i = blockIdx.x * 256 + threadIdx.x;
  if (i < NBINS) hist[i] = 0;
}

__global__ void __launch_bounds__(256) hist_kernel(const float* __restrict__ coords,
                                                   uint32_t* __restrict__ hist, int N) {
  int i = blockIdx.x * 256 + threadIdx.x;
  if (i >= N) return;
  int b = bin_of(coords[3 * i], coords[3 * i + 1], coords[3 * i + 2]);
  atomicAdd(&hist[b], 1u);
}

// one block of 1024 threads; each owns 32 consecutive bins
__global__ void __launch_bounds__(1024) scan_kernel(const uint32_t* __restrict__ hist,
                                                    uint32_t* __restrict__ offs) {
  __shared__ uint32_t s[1024];
  int t = threadIdx.x;
  uint32_t sum = 0;
#pragma unroll
  for (int k = 0; k < 32; ++k) sum += hist[t * 32 + k];
  s[t] = sum;
  __syncthreads();
  for (int d = 1; d < 1024; d <<= 1) {
    uint32_t v = (t >= d) ? s[t - d] : 0;
    __syncthreads();
    s[t] += v;
    __syncthreads();
  }
  uint32_t run = (t == 0) ? 0 : s[t - 1];
#pragma unroll
  for (int k = 0; k < 32; ++k) {
    offs[t * 32 + k] = run;
    run += hist[t * 32 + k];
  }
}

__global__ void __launch_bounds__(256) scatter_kernel(const float* __restrict__ coords,
                                                      uint32_t* __restrict__ offs,
                                                      float4* __restrict__ sorted, int N) {
  int i = blockIdx.x * 256 + threadIdx.x;
  if (i >= N) return;
  float x = coords[3 * i], y = coords[3 * i + 1], z = coords[3 * i + 2];
  int b = bin_of(x, y, z);
  uint32_t pos = atomicAdd(&offs[b], 1u);
  float4 v; v.x = x; v.y = y; v.z = z; v.w = __int_as_float(i);
  sorted[pos] = v;
}

// ---------------- prep kernels ----------------

__device__ __forceinline__ float comb_row(const float* __restrict__ B, int r, int j) {
  return (r < 32) ? (B[r * 64 + j] + B[(r + 32) * 64 + j]) : B[(r + 32) * 64 + j];
}

__device__ __forceinline__ uint32_t pack_bf16(float v0, float v1) {
  uint32_t a = __float_as_uint(v0);
  uint32_t b = __float_as_uint(v1);
  uint32_t r0 = (a + 0x7fffu + ((a >> 16) & 1u)) >> 16;     // RNE
  uint32_t r1 = (b + 0x7fffu + ((b >> 16) & 1u)) >> 16;
  return (r0 & 0xffffu) | (r1 << 16);
}

// Bf[seg=3][cb=4][lane=64] = uint4 (8 bf16, k=(lane>>4)*8+e, j=cb*16+(lane&15)), invS folded
__global__ void __launch_bounds__(256) make_bfrag(const float* __restrict__ B, uint4* __restrict__ Bf) {
  int i = blockIdx.x * 256 + threadIdx.x;
  if (i >= 768) return;
  int lane = i & 63;
  int cb = (i >> 6) & 3;
  int seg = i >> 8;
  float invS = (seg == 0) ? (1.0f / S3) : (seg == 1) ? (1.0f / S2) : (1.0f / SV);
  int j = cb * 16 + (lane & 15);
  int h = lane >> 4;
  uint32_t o[4];
#pragma unroll
  for (int r = 0; r < 4; ++r) {
    int k0 = seg * 32 + h * 8 + 2 * r;
    float v0 = comb_row(B, k0, j) * invS;
    float v1 = comb_row(B, k0 + 1, j) * invS;
    o[r] = pack_bf16(v0, v1);
  }
  uint4 st; st.x = o[0]; st.y = o[1]; st.z = o[2]; st.w = o[3];
  Bf[(seg * 4 + cb) * 64 + lane] = st;
}

// Transpose+quantize (P, 32, H, W) fp32 -> (P, H, Wp, 32) fp8 e4m3 scaled by S,
// with x-padding: texel x stored at slot x+1; slot 0 = texel 0; slots W+1,W+2 = texel W-1.
__global__ void __launch_bounds__(256) transpose_cl8(const float* __restrict__ in,
                                                     uint8_t* __restrict__ out,
                                                     int H, int W, int Wp, int nxt, float S) {
  __shared__ float tile[32][65];
  int b = blockIdx.x;
  int xt = b % nxt;
  int tmp = b / nxt;
  int y = tmp % H;
  int p = tmp / H;
  int x0 = xt * 64;
  int lane = threadIdx.x;
  const float* src = in + ((size_t)p * 32 * (size_t)H) * (size_t)W + (size_t)y * (size_t)W;
  int cx = lane & 63;
  int c4 = lane >> 6;
#pragma unroll
  for (int pass = 0; pass < 8; ++pass) {
    int c = pass * 4 + c4;
    tile[c][cx] = src[(size_t)c * (size_t)(H) * (size_t)W + x0 + cx];
  }
  __syncthreads();
  int xx = lane >> 2;
  int c8 = (lane & 3) * 8;
  float f[8];
#pragma unroll
  for (int i = 0; i < 8; ++i) f[i] = tile[c8 + i][xx] * S;
  uint32_t lo = 0, hi = 0;
  lo = (uint32_t)__builtin_amdgcn_cvt_pk_fp8_f32(f[0], f[1], (int)lo, false);
  lo = (uint32_t)__builtin_amdgcn_cvt_pk_fp8_f32(f[2], f[3], (int)lo, true);
  hi = (uint32_t)__builtin_amdgcn_cvt_pk_fp8_f32(f[4], f[5], (int)hi, false);
  hi = (uint32_t)__builtin_amdgcn_cvt_pk_fp8_f32(f[6], f[7], (int)hi, true);
  uint2 st; st.x = lo; st.y = hi;
  int x = x0 + xx;
  uint8_t* rowb = out + (((size_t)p * H + y) * (size_t)Wp) * 32;
  *reinterpret_cast<uint2*>(rowb + (size_t)(x + 1) * 32 + c8) = st;
  if (x == 0)
    *reinterpret_cast<uint2*>(rowb + c8) = st;
  if (x == W - 1) {
    *reinterpret_cast<uint2*>(rowb + (size_t)(W + 1) * 32 + c8) = st;
    *reinterpret_cast<uint2*>(rowb + (size_t)(W + 2) * 32 + c8) = st;
  }
}

// ---------------- main kernel: sorted window gathers, MFMA projection ----------------

__global__ void __launch_bounds__(256, 4) triplane_main(
    const float4* __restrict__ sorted, // (N) x (x,y,z,idx)
    const uint8_t* __restrict__ p3t,   // (3,128,132,32) fp8, x-padded
    const uint8_t* __restrict__ p2t,   // (3,256,260,32) fp8
    const uint8_t* __restrict__ vt,    // (3,516,32) fp8
    const uint4* __restrict__ Bfrag,   // [3][4][64] uint4
    float* __restrict__ out, int N) {
  int t = blockIdx.x * 256 + threadIdx.x;
  int l = threadIdx.x & 63;
  int n0 = (blockIdx.x * 256 + (threadIdx.x & ~63)) >> 2;  // first point of this wave
  if (n0 >= N) return;
  int n = t >> 2;
  int q = l & 3;
  bool hiq = (q >> 1) != 0;   // texel-pair selector
  int q16 = q * 16;

  float4 pd = sorted[n];
  float x = pd.x;
  float y = pd.y;
  float z = pd.z;
  int oidx = __float_as_int(pd.w);

  f32x2 feat2[24];   // [seg=3][8]: entry e = channels {2e,2e+1} of this lane's 16-ch half
#pragma unroll
  for (int i = 0; i < 24; ++i) { feat2[i].x = 0.f; feat2[i].y = 0.f; }

  uint4 rA[8], rB[8];

  // ======== scale 3 (H=128) ========
  float wx[4], wy[4], wz[4];
  int cbx, cby, roy[4], roz[4];
  axis_w(x, 128, wx, &cbx);
  axis_wr(y, 128, STRIDE3, wy, &cby, roy);
  axis_r(z, 128, STRIDE3, wz, roz);
  float cx0 = hiq ? wx[1] : wx[0], cx1 = hiq ? wx[3] : wx[2];
  float cy0 = hiq ? wy[1] : wy[0], cy1 = hiq ? wy[3] : wy[2];

  const uint8_t* b3 = p3t + q16;
  issueW(b3,           roy, cbx, rA);   // xy: rows y, cols x
  issueW(b3 + 1 * PL3, roz, cby, rB);   // yz: rows z, cols y
  consumeW(wy, cx0, cx1, rA, feat2 + 0);
  issueW(b3 + 2 * PL3, roz, cbx, rA);   // xz: rows z, cols x
  consumeW(wz, cy0, cy1, rB, feat2 + 0);

  // ======== scale 2 (H=256) ========
  float wx2[4], wy2[4], wz2[4];
  int cbx2, cby2, roy2[4], roz2[4];
  axis_w(x, 256, wx2, &cbx2);
  axis_wr(y, 256, STRIDE2, wy2, &cby2, roy2);
  axis_r(z, 256, STRIDE2, wz2, roz2);
  float cx20 = hiq ? wx2[1] : wx2[0], cx21 = hiq ? wx2[3] : wx2[2];
  float cy20 = hiq ? wy2[1] : wy2[0], cy21 = hiq ? wy2[3] : wy2[2];

  const uint8_t* b2 = p2t + q16;
  issueW(b2,           roy2, cbx2, rB);               // p2 xy
  consumeW(wz, cx0, cx1, rA, feat2 + 0);              // p3 xz
  issueW(b2 + 1 * PL2, roz2, cby2, rA);               // p2 yz
  consumeW(wy2, cx20, cx21, rB, feat2 + 8);           // p2 xy
  issueW(b2 + 2 * PL2, roz2, cbx2, rB);               // p2 xz
  consumeW(wz2, cy20, cy21, rA, feat2 + 8);           // p2 yz

  // ======== vector (W=512) ========
  float wvx[4], wvy[4], wvz[4];
  int cbvx, cbvy, cbvz;
  axis_w(x, 512, wvx, &cbvx);
  axis_w(y, 512, wvy, &cbvy);
  axis_w(z, 512, wvz, &cbvz);
  {
    const uint8_t* v0 = vt + q16;
    rA[0] = *reinterpret_cast<const uint4*>(v0 + cbvx);
    rA[1] = *reinterpret_cast<const uint4*>(v0 + cbvx + 64);
    rA[2] = *reinterpret_cast<const uint4*>(v0 + PLV + cbvy);
    rA[3] = *reinterpret_cast<const uint4*>(v0 + PLV + cbvy + 64);
    rA[4] = *reinterpret_cast<const uint4*>(v0 + 2 * PLV + cbvz);
    rA[5] = *reinterpret_cast<const uint4*>(v0 + 2 * PLV + cbvz + 64);
  }
  consumeW(wz2, cx20, cx21, rB, feat2 + 8);           // p2 xz
  {
    float a0 = hiq ? wvx[1] : wvx[0], a1 = hiq ? wvx[3] : wvx[2];
    float b0 = hiq ? wvy[1] : wvy[0], b1 = hiq ? wvy[3] : wvy[2];
    float c0 = hiq ? wvz[1] : wvz[0], c1 = hiq ? wvz[3] : wvz[2];
    consume16(rA[0], a0, feat2 + 16);
    consume16(rA[1], a1, feat2 + 16);
    consume16(rA[2], b0, feat2 + 16);
    consume16(rA[3], b1, feat2 + 16);
    consume16(rA[4], c0, feat2 + 16);
    consume16(rA[5], c1, feat2 + 16);
  }

  // ---- pair-reduce (lane q with lane q^2) + pack own k-quarter to bf16 ----
  // lane q owns quarter qq = ((q&1)<<1)|(q>>1): half q&1, channel offset 8*(q>>1)
  uint32_t packed[12];
#pragma unroll
  for (int s = 0; s < 3; ++s) {
#pragma unroll
    for (int r = 0; r < 4; ++r) {
      f32x2 lo = feat2[s * 8 + r];
      f32x2 hi = feat2[s * 8 + 4 + r];
      float ownx = hiq ? hi.x : lo.x, owny = hiq ? hi.y : lo.y;
      float sndx = hiq ? lo.x : hi.x, sndy = hiq ? lo.y : hi.y;
      float rx = ownx + __shfl_xor(sndx, 2);
      float ry = owny + __shfl_xor(sndy, 2);
      uint32_t pk;
      asm("v_cvt_pk_bf16_f32 %0, %1, %2" : "=v"(pk) : "v"(rx), "v"(ry));
      packed[s * 4 + r] = pk;
    }
  }

  // ---- redistribute to MFMA A-fragment: dest lane 16h'+p pulls quarter h' of point p.
  // quarter h' lives in lane 4p + ((h'&1)<<1 | h'>>1)
  int hp = l >> 4;
  int srcq = ((hp & 1) << 1) | (hp >> 1);
  int baddr = (4 * (l & 15) + srcq) * 4;
  uint32_t apk[12];
#pragma unroll
  for (int i = 0; i < 12; ++i)
    apk[i] = (uint32_t)__builtin_amdgcn_ds_bpermute(baddr, (int)packed[i]);

  // ---- output rows for this lane's 4 epilogue points (orig indices via shfl) ----
  int rowr[4];
#pragma unroll
  for (int reg = 0; reg < 4; ++reg)
    rowr[reg] = __shfl(oidx, 16 * hp + 4 * reg);

  // ---- load B fragments ----
  uint4 bfr[12];
#pragma unroll
  for (int i = 0; i < 12; ++i) bfr[i] = Bfrag[i * 64 + l];

  // ---- 12 MFMAs ----
  union U { uint32_t u[4]; s16x8 v; };
  f32x4 acc[4];
#pragma unroll
  for (int cb = 0; cb < 4; ++cb) { acc[cb].x = 0.f; acc[cb].y = 0.f; acc[cb].z = 0.f; acc[cb].w = 0.f; }
#pragma unroll
  for (int seg = 0; seg < 3; ++seg) {
    U a;
    a.u[0] = apk[seg * 4 + 0];
    a.u[1] = apk[seg * 4 + 1];
    a.u[2] = apk[seg * 4 + 2];
    a.u[3] = apk[seg * 4 + 3];
#pragma unroll
    for (int cb = 0; cb < 4; ++cb) {
      U b;
      b.u[0] = bfr[seg * 4 + cb].x;
      b.u[1] = bfr[seg * 4 + cb].y;
      b.u[2] = bfr[seg * 4 + cb].z;
      b.u[3] = bfr[seg * 4 + cb].w;
      acc[cb] = __builtin_amdgcn_mfma_f32_16x16x32_bf16(a.v, b.v, acc[cb], 0, 0, 0);
    }
  }

  // ---- epilogue: sin/cos + store. C/D: row (=point) = (l>>4)*4+reg, col = l&15 ----
  int jc = l & 15;
#pragma unroll
  for (int cb = 0; cb < 4; ++cb) {
#pragma unroll
    for (int reg = 0; reg < 4; ++reg) {
      float v = acc[cb][reg];
      float sv = __builtin_amdgcn_sinf(v);   // reference is sin(2*pi*dot); v_sin takes revolutions
      float cv = __builtin_amdgcn_cosf(v);
      float* po = out + (size_t)rowr[reg] * 128 + cb * 16 + jc;
      po[0] = sv;
      po[64] = cv;
    }
  }
}

// ---------------- launcher ----------------

extern "C" void kernel_launch(void* const* d_in, const int* in_sizes, int n_in,
                              void* d_out, int out_size, void* d_ws, size_t ws_size,
                              hipStream_t stream) {
  const float* coords = (const float*)d_in[0];
  const float* plane3 = (const float*)d_in[1];
  const float* plane2 = (const float*)d_in[2];
  const float* vec1   = (const float*)d_in[3];
  const float* B      = (const float*)d_in[4];
  float* out = (float*)d_out;
  int N = in_sizes[0] / 3;

  char* ws = (char*)d_ws;
  size_t off = 0;
  auto take = [&](size_t bytes) { size_t o = off; off = (off + bytes + 4095) & ~(size_t)4095; return o; };
  const size_t off_p3 = take((size_t)3 * PL3);
  const size_t off_p2 = take((size_t)3 * PL2);
  const size_t off_vt = take((size_t)3 * PLV);
  const size_t off_bf = take(768 * 16);
  const size_t off_hist = take(NBINS * 4);
  const size_t off_offs = take(NBINS * 4);
  const size_t off_sorted = take((size_t)N * 16);
  uint8_t* p3t = (uint8_t*)(ws + off_p3);
  uint8_t* p2t = (uint8_t*)(ws + off_p2);
  uint8_t* vt  = (uint8_t*)(ws + off_vt);
  uint4* Bf = (uint4*)(ws + off_bf);
  uint32_t* hist = (uint32_t*)(ws + off_hist);
  uint32_t* offs = (uint32_t*)(ws + off_offs);
  float4* sorted = (float4*)(ws + off_sorted);

  hipLaunchKernelGGL(make_bfrag, dim3(3), dim3(256), 0, stream, B, Bf);
  hipLaunchKernelGGL(transpose_cl8, dim3(3 * 128 * 2), dim3(256), 0, stream, plane3, p3t, 128, 128, 132, 2, S3);
  hipLaunchKernelGGL(transpose_cl8, dim3(3 * 256 * 4), dim3(256), 0, stream, plane2, p2t, 256, 256, 260, 4, S2);
  hipLaunchKernelGGL(transpose_cl8, dim3(3 * 1 * 8), dim3(256), 0, stream, vec1, vt, 1, 512, 516, 8, SV);
  hipLaunchKernelGGL(zero_hist, dim3(NBINS / 256), dim3(256), 0, stream, hist);
  hipLaunchKernelGGL(hist_kernel, dim3((N + 255) / 256), dim3(256), 0, stream, coords, hist, N);
  hipLaunchKernelGGL(scan_kernel, dim3(1), dim3(1024), 0, stream, hist, offs);
  hipLaunchKernelGGL(scatter_kernel, dim3((N + 255) / 256), dim3(256), 0, stream, coords, offs, sorted, N);
  hipLaunchKernelGGL(triplane_main, dim3((N * 4 + 255) / 256), dim3(256), 0, stream,
                     sorted, p3t, p2t, vt, Bf, out, N);
}

// Round 10
// 186.419 us; speedup vs baseline: 1.5225x; 1.0548x over previous
//
#include <hip/hip_runtime.h>
#include <hip/hip_bf16.h>
#include <stdint.h>

typedef float f32x2 __attribute__((ext_vector_type(2)));
typedef float f32x4 __attribute__((ext_vector_type(4)));
typedef short s16x8 __attribute__((ext_vector_type(8)));

#define CUBIC_A (-0.75f)
#define S3 262144.0f   // 2^18 scale for plane3
#define S2 131072.0f   // 2^17 scale for plane2
#define SV 32768.0f    // 2^15 scale for vec

// padded plane geometry (x-axis padded with clamped border texels at both ends)
#define PL3 (128 * 132 * 32)   // per-plane bytes, scale 3 (H=128, Wp=132)
#define PL2 (256 * 260 * 32)   // scale 2 (H=256, Wp=260)
#define PLV (516 * 32)         // vec (Wp=516)
#define STRIDE3 (132 * 32)
#define STRIDE2 (260 * 32)

#define NBINS 32768            // 5 bits per axis

__device__ __forceinline__ void cubic_w(float t, float* w) {
  float s = t + 1.0f;
  w[0] = ((CUBIC_A * s - 5.0f * CUBIC_A) * s + 8.0f * CUBIC_A) * s - 4.0f * CUBIC_A;
  w[1] = ((CUBIC_A + 2.0f) * t - (CUBIC_A + 3.0f)) * t * t + 1.0f;
  float u = 1.0f - t;
  w[2] = ((CUBIC_A + 2.0f) * u - (CUBIC_A + 3.0f)) * u * u + 1.0f;
  float v = 2.0f - t;
  w[3] = ((CUBIC_A * v - 5.0f * CUBIC_A) * v + 8.0f * CUBIC_A) * v - 4.0f * CUBIC_A;
}

// col-axis: weights + window base byte (padded layout: window start x0-1 -> byte x0*32)
__device__ __forceinline__ void axis_w(float c, int size, float* w, int* colb) {
  float ix = (c + 1.0f) * 0.5f * (float)(size - 1);
  float x0f = floorf(ix);
  cubic_w(ix - x0f, w);
  *colb = (int)x0f * 32;
}

// row-axis: weights + clamped row byte offsets
__device__ __forceinline__ void axis_r(float c, int size, int strideB, float* w, int* ro) {
  float ix = (c + 1.0f) * 0.5f * (float)(size - 1);
  float x0f = floorf(ix);
  cubic_w(ix - x0f, w);
  int x0 = (int)x0f;
#pragma unroll
  for (int k = 0; k < 4; ++k) {
    int qq = x0 - 1 + k;
    qq = qq < 0 ? 0 : qq;
    qq = qq > size - 1 ? size - 1 : qq;
    ro[k] = qq * strideB;
  }
}

// both (y axis is used as rows and cols)
__device__ __forceinline__ void axis_wr(float c, int size, int strideB, float* w, int* colb, int* ro) {
  float ix = (c + 1.0f) * 0.5f * (float)(size - 1);
  float x0f = floorf(ix);
  cubic_w(ix - x0f, w);
  int x0 = (int)x0f;
  *colb = x0 * 32;
#pragma unroll
  for (int k = 0; k < 4; ++k) {
    int qq = x0 - 1 + k;
    qq = qq < 0 ? 0 : qq;
    qq = qq > size - 1 ? size - 1 : qq;
    ro[k] = qq * strideB;
  }
}

// issue 8 x 16B loads: 4 rows x 2 half-windows (lane's q*16 already folded into base)
__device__ __forceinline__ void issueW(const uint8_t* __restrict__ base,
                                       const int* ro, int cb, uint4* r) {
#pragma unroll
  for (int i = 0; i < 4; ++i) {
    r[2 * i]     = *reinterpret_cast<const uint4*>(base + ro[i] + cb);
    r[2 * i + 1] = *reinterpret_cast<const uint4*>(base + ro[i] + cb + 64);
  }
}

// unpack 16 fp8 channels with one weight into acc8 (8 f32x2 = 16 ch)
__device__ __forceinline__ void consume16(uint4 v, float w, f32x2* acc8) {
  f32x2 w2; w2.x = w; w2.y = w;
  acc8[0] += w2 * __builtin_amdgcn_cvt_pk_f32_fp8((int)v.x, false);
  acc8[1] += w2 * __builtin_amdgcn_cvt_pk_f32_fp8((int)v.x, true);
  acc8[2] += w2 * __builtin_amdgcn_cvt_pk_f32_fp8((int)v.y, false);
  acc8[3] += w2 * __builtin_amdgcn_cvt_pk_f32_fp8((int)v.y, true);
  acc8[4] += w2 * __builtin_amdgcn_cvt_pk_f32_fp8((int)v.z, false);
  acc8[5] += w2 * __builtin_amdgcn_cvt_pk_f32_fp8((int)v.z, true);
  acc8[6] += w2 * __builtin_amdgcn_cvt_pk_f32_fp8((int)v.w, false);
  acc8[7] += w2 * __builtin_amdgcn_cvt_pk_f32_fp8((int)v.w, true);
}

// consume one plane sample: 4 rows x {texel p0 (w=wr*cw0), texel p0+2 (w=wr*cw1)}
__device__ __forceinline__ void consumeW(const float* wr, float cw0, float cw1,
                                         const uint4* r, f32x2* acc8) {
#pragma unroll
  for (int i = 0; i < 4; ++i) {
    consume16(r[2 * i],     wr[i] * cw0, acc8);
    consume16(r[2 * i + 1], wr[i] * cw1, acc8);
  }
}

// ---------------- sort helpers ----------------

__device__ __forceinline__ int bin_of(float x, float y, float z) {
  int bx = (int)((x + 1.0f) * 16.0f); bx = bx < 0 ? 0 : (bx > 31 ? 31 : bx);
  int by = (int)((y + 1.0f) * 16.0f); by = by < 0 ? 0 : (by > 31 ? 31 : by);
  int bz = (int)((z + 1.0f) * 16.0f); bz = bz < 0 ? 0 : (bz > 31 ? 31 : bz);
  return (bz << 10) | (by << 5) | bx;   // x fastest
}

// ---------------- fused prep device functions ----------------

__device__ __forceinline__ float comb_row(const float* __restrict__ B, int r, int j) {
  return (r < 32) ? (B[r * 64 + j] + B[(r + 32) * 64 + j]) : B[(r + 32) * 64 + j];
}

__device__ __forceinline__ uint32_t pack_bf16(float v0, float v1) {
  uint32_t a = __float_as_uint(v0);
  uint32_t b = __float_as_uint(v1);
  uint32_t r0 = (a + 0x7fffu + ((a >> 16) & 1u)) >> 16;     // RNE
  uint32_t r1 = (b + 0x7fffu + ((b >> 16) & 1u)) >> 16;
  return (r0 & 0xffffu) | (r1 << 16);
}

__device__ __forceinline__ void bfrag_body(int i, const float* __restrict__ B, uint4* __restrict__ Bf) {
  if (i >= 768) return;
  int lane = i & 63;
  int cb = (i >> 6) & 3;
  int seg = i >> 8;
  float invS = (seg == 0) ? (1.0f / S3) : (seg == 1) ? (1.0f / S2) : (1.0f / SV);
  int j = cb * 16 + (lane & 15);
  int h = lane >> 4;
  uint32_t o[4];
#pragma unroll
  for (int r = 0; r < 4; ++r) {
    int k0 = seg * 32 + h * 8 + 2 * r;
    float v0 = comb_row(B, k0, j) * invS;
    float v1 = comb_row(B, k0 + 1, j) * invS;
    o[r] = pack_bf16(v0, v1);
  }
  uint4 st; st.x = o[0]; st.y = o[1]; st.z = o[2]; st.w = o[3];
  Bf[(seg * 4 + cb) * 64 + lane] = st;
}

// Transpose+quantize (P, 32, H, W) fp32 -> (P, H, Wp, 32) fp8 e4m3 scaled by S,
// with x-padding: texel x stored at slot x+1; slot 0 = texel 0; slots W+1,W+2 = texel W-1.
__device__ __forceinline__ void transpose_body(int b, const float* __restrict__ in,
                                               uint8_t* __restrict__ out,
                                               int H, int W, int Wp, int nxt, float S) {
  __shared__ float tile[32][65];
  int xt = b % nxt;
  int tmp = b / nxt;
  int y = tmp % H;
  int p = tmp / H;
  int x0 = xt * 64;
  int lane = threadIdx.x;
  const float* src = in + ((size_t)p * 32 * (size_t)H) * (size_t)W + (size_t)y * (size_t)W;
  int cx = lane & 63;
  int c4 = lane >> 6;
#pragma unroll
  for (int pass = 0; pass < 8; ++pass) {
    int c = pass * 4 + c4;
    tile[c][cx] = src[(size_t)c * (size_t)(H) * (size_t)W + x0 + cx];
  }
  __syncthreads();
  int xx = lane >> 2;
  int c8 = (lane & 3) * 8;
  float f[8];
#pragma unroll
  for (int i = 0; i < 8; ++i) f[i] = tile[c8 + i][xx] * S;
  uint32_t lo = 0, hi = 0;
  lo = (uint32_t)__builtin_amdgcn_cvt_pk_fp8_f32(f[0], f[1], (int)lo, false);
  lo = (uint32_t)__builtin_amdgcn_cvt_pk_fp8_f32(f[2], f[3], (int)lo, true);
  hi = (uint32_t)__builtin_amdgcn_cvt_pk_fp8_f32(f[4], f[5], (int)hi, false);
  hi = (uint32_t)__builtin_amdgcn_cvt_pk_fp8_f32(f[6], f[7], (int)hi, true);
  uint2 st; st.x = lo; st.y = hi;
  int x = x0 + xx;
  uint8_t* rowb = out + (((size_t)p * H + y) * (size_t)Wp) * 32;
  *reinterpret_cast<uint2*>(rowb + (size_t)(x + 1) * 32 + c8) = st;
  if (x == 0)
    *reinterpret_cast<uint2*>(rowb + c8) = st;
  if (x == W - 1) {
    *reinterpret_cast<uint2*>(rowb + (size_t)(W + 1) * 32 + c8) = st;
    *reinterpret_cast<uint2*>(rowb + (size_t)(W + 2) * 32 + c8) = st;
  }
}

// fused prep: [0,3) bfrag | [3,131) zero hist | [131,899) p3 | [899,3971) p2 | [3971,3995) vec
#define PREP_BLOCKS 3995
__global__ void __launch_bounds__(256) prep_all(const float* __restrict__ B, uint4* __restrict__ Bf,
                                                uint32_t* __restrict__ hist,
                                                const float* __restrict__ plane3, uint8_t* __restrict__ p3t,
                                                const float* __restrict__ plane2, uint8_t* __restrict__ p2t,
                                                const float* __restrict__ vec1, uint8_t* __restrict__ vt) {
  int bid = blockIdx.x;
  if (bid < 3) {
    bfrag_body(bid * 256 + threadIdx.x, B, Bf);
  } else if (bid < 131) {
    int i = (bid - 3) * 256 + threadIdx.x;
    if (i < NBINS) hist[i] = 0;
  } else if (bid < 899) {
    transpose_body(bid - 131, plane3, p3t, 128, 128, 132, 2, S3);
  } else if (bid < 3971) {
    transpose_body(bid - 899, plane2, p2t, 256, 256, 260, 4, S2);
  } else {
    transpose_body(bid - 3971, vec1, vt, 1, 512, 516, 8, SV);
  }
}

// ---------------- sort kernels ----------------

__global__ void __launch_bounds__(256) hist_kernel(const float* __restrict__ coords,
                                                   uint32_t* __restrict__ hist, int N) {
  int i = blockIdx.x * 256 + threadIdx.x;
  if (i >= N) return;
  int b = bin_of(coords[3 * i], coords[3 * i + 1], coords[3 * i + 2]);
  atomicAdd(&hist[b], 1u);
}

// one block of 1024 threads; each owns 32 consecutive bins
__global__ void __launch_bounds__(1024) scan_kernel(const uint32_t* __restrict__ hist,
                                                    uint32_t* __restrict__ offs) {
  __shared__ uint32_t s[1024];
  int t = threadIdx.x;
  uint32_t sum = 0;
#pragma unroll
  for (int k = 0; k < 32; ++k) sum += hist[t * 32 + k];
  s[t] = sum;
  __syncthreads();
  for (int d = 1; d < 1024; d <<= 1) {
    uint32_t v = (t >= d) ? s[t - d] : 0;
    __syncthreads();
    s[t] += v;
    __syncthreads();
  }
  uint32_t run = (t == 0) ? 0 : s[t - 1];
#pragma unroll
  for (int k = 0; k < 32; ++k) {
    offs[t * 32 + k] = run;
    run += hist[t * 32 + k];
  }
}

__global__ void __launch_bounds__(256) scatter_kernel(const float* __restrict__ coords,
                                                      uint32_t* __restrict__ offs,
                                                      float4* __restrict__ sorted, int N) {
  int i = blockIdx.x * 256 + threadIdx.x;
  if (i >= N) return;
  float x = coords[3 * i], y = coords[3 * i + 1], z = coords[3 * i + 2];
  int b = bin_of(x, y, z);
  uint32_t pos = atomicAdd(&offs[b], 1u);
  float4 v; v.x = x; v.y = y; v.z = z; v.w = __int_as_float(i);
  sorted[pos] = v;
}

// ---------------- main kernel: sorted window gathers, MFMA projection ----------------

__global__ void __launch_bounds__(256, 6) triplane_main(
    const float4* __restrict__ sorted, // (N) x (x,y,z,idx)
    const uint8_t* __restrict__ p3t,   // (3,128,132,32) fp8, x-padded
    const uint8_t* __restrict__ p2t,   // (3,256,260,32) fp8
    const uint8_t* __restrict__ vt,    // (3,516,32) fp8
    const uint4* __restrict__ Bfrag,   // [3][4][64] uint4
    float* __restrict__ out, int N) {
  int t = blockIdx.x * 256 + threadIdx.x;
  int l = threadIdx.x & 63;
  int n0 = (blockIdx.x * 256 + (threadIdx.x & ~63)) >> 2;  // first point of this wave
  if (n0 >= N) return;
  int n = t >> 2;
  int q = l & 3;
  bool hiq = (q >> 1) != 0;   // texel-pair selector
  int q16 = q * 16;

  float4 pd = sorted[n];
  float x = pd.x;
  float y = pd.y;
  float z = pd.z;
  int oidx = __float_as_int(pd.w);

  f32x2 feat2[24];   // [seg=3][8]: entry e = channels {2e,2e+1} of this lane's 16-ch half
#pragma unroll
  for (int i = 0; i < 24; ++i) { feat2[i].x = 0.f; feat2[i].y = 0.f; }

  uint4 rA[8], rB[8];

  // ======== scale 3 (H=128) ========
  float wx[4], wy[4], wz[4];
  int cbx, cby, roy[4], roz[4];
  axis_w(x, 128, wx, &cbx);
  axis_wr(y, 128, STRIDE3, wy, &cby, roy);
  axis_r(z, 128, STRIDE3, wz, roz);
  float cx0 = hiq ? wx[1] : wx[0], cx1 = hiq ? wx[3] : wx[2];
  float cy0 = hiq ? wy[1] : wy[0], cy1 = hiq ? wy[3] : wy[2];

  const uint8_t* b3 = p3t + q16;
  issueW(b3,           roy, cbx, rA);   // xy: rows y, cols x
  issueW(b3 + 1 * PL3, roz, cby, rB);   // yz: rows z, cols y
  consumeW(wy, cx0, cx1, rA, feat2 + 0);
  issueW(b3 + 2 * PL3, roz, cbx, rA);   // xz: rows z, cols x
  consumeW(wz, cy0, cy1, rB, feat2 + 0);

  // ======== scale 2 (H=256) ========
  float wx2[4], wy2[4], wz2[4];
  int cbx2, cby2, roy2[4], roz2[4];
  axis_w(x, 256, wx2, &cbx2);
  axis_wr(y, 256, STRIDE2, wy2, &cby2, roy2);
  axis_r(z, 256, STRIDE2, wz2, roz2);
  float cx20 = hiq ? wx2[1] : wx2[0], cx21 = hiq ? wx2[3] : wx2[2];
  float cy20 = hiq ? wy2[1] : wy2[0], cy21 = hiq ? wy2[3] : wy2[2];

  const uint8_t* b2 = p2t + q16;
  issueW(b2,           roy2, cbx2, rB);               // p2 xy
  consumeW(wz, cx0, cx1, rA, feat2 + 0);              // p3 xz
  issueW(b2 + 1 * PL2, roz2, cby2, rA);               // p2 yz
  consumeW(wy2, cx20, cx21, rB, feat2 + 8);           // p2 xy
  issueW(b2 + 2 * PL2, roz2, cbx2, rB);               // p2 xz
  consumeW(wz2, cy20, cy21, rA, feat2 + 8);           // p2 yz

  // ======== vector (W=512) ========
  float wvx[4], wvy[4], wvz[4];
  int cbvx, cbvy, cbvz;
  axis_w(x, 512, wvx, &cbvx);
  axis_w(y, 512, wvy, &cbvy);
  axis_w(z, 512, wvz, &cbvz);
  {
    const uint8_t* v0 = vt + q16;
    rA[0] = *reinterpret_cast<const uint4*>(v0 + cbvx);
    rA[1] = *reinterpret_cast<const uint4*>(v0 + cbvx + 64);
    rA[2] = *reinterpret_cast<const uint4*>(v0 + PLV + cbvy);
    rA[3] = *reinterpret_cast<const uint4*>(v0 + PLV + cbvy + 64);
    rA[4] = *reinterpret_cast<const uint4*>(v0 + 2 * PLV + cbvz);
    rA[5] = *reinterpret_cast<const uint4*>(v0 + 2 * PLV + cbvz + 64);
  }
  consumeW(wz2, cx20, cx21, rB, feat2 + 8);           // p2 xz
  {
    float a0 = hiq ? wvx[1] : wvx[0], a1 = hiq ? wvx[3] : wvx[2];
    float b0 = hiq ? wvy[1] : wvy[0], b1 = hiq ? wvy[3] : wvy[2];
    float c0 = hiq ? wvz[1] : wvz[0], c1 = hiq ? wvz[3] : wvz[2];
    consume16(rA[0], a0, feat2 + 16);
    consume16(rA[1], a1, feat2 + 16);
    consume16(rA[2], b0, feat2 + 16);
    consume16(rA[3], b1, feat2 + 16);
    consume16(rA[4], c0, feat2 + 16);
    consume16(rA[5], c1, feat2 + 16);
  }

  // ---- pair-reduce (lane q with lane q^2) + pack own k-quarter to bf16 ----
  // lane q owns quarter qq = ((q&1)<<1)|(q>>1): half q&1, channel offset 8*(q>>1)
  uint32_t packed[12];
#pragma unroll
  for (int s = 0; s < 3; ++s) {
#pragma unroll
    for (int r = 0; r < 4; ++r) {
      f32x2 lo = feat2[s * 8 + r];
      f32x2 hi = feat2[s * 8 + 4 + r];
      float ownx = hiq ? hi.x : lo.x, owny = hiq ? hi.y : lo.y;
      float sndx = hiq ? lo.x : hi.x, sndy = hiq ? lo.y : hi.y;
      float rx = ownx + __shfl_xor(sndx, 2);
      float ry = owny + __shfl_xor(sndy, 2);
      uint32_t pk;
      asm("v_cvt_pk_bf16_f32 %0, %1, %2" : "=v"(pk) : "v"(rx), "v"(ry));
      packed[s * 4 + r] = pk;
    }
  }

  // ---- redistribute to MFMA A-fragment: dest lane 16h'+p pulls quarter h' of point p.
  // quarter h' lives in lane 4p + ((h'&1)<<1 | h'>>1)
  int hp = l >> 4;
  int srcq = ((hp & 1) << 1) | (hp >> 1);
  int baddr = (4 * (l & 15) + srcq) * 4;
  uint32_t apk[12];
#pragma unroll
  for (int i = 0; i < 12; ++i)
    apk[i] = (uint32_t)__builtin_amdgcn_ds_bpermute(baddr, (int)packed[i]);

  // ---- output rows for this lane's 4 epilogue points (orig indices via shfl) ----
  int rowr[4];
#pragma unroll
  for (int reg = 0; reg < 4; ++reg)
    rowr[reg] = __shfl(oidx, 16 * hp + 4 * reg);

  // ---- load B fragments ----
  uint4 bfr[12];
#pragma unroll
  for (int i = 0; i < 12; ++i) bfr[i] = Bfrag[i * 64 + l];

  // ---- 12 MFMAs ----
  union U { uint32_t u[4]; s16x8 v; };
  f32x4 acc[4];
#pragma unroll
  for (int cb = 0; cb < 4; ++cb) { acc[cb].x = 0.f; acc[cb].y = 0.f; acc[cb].z = 0.f; acc[cb].w = 0.f; }
#pragma unroll
  for (int seg = 0; seg < 3; ++seg) {
    U a;
    a.u[0] = apk[seg * 4 + 0];
    a.u[1] = apk[seg * 4 + 1];
    a.u[2] = apk[seg * 4 + 2];
    a.u[3] = apk[seg * 4 + 3];
#pragma unroll
    for (int cb = 0; cb < 4; ++cb) {
      U b;
      b.u[0] = bfr[seg * 4 + cb].x;
      b.u[1] = bfr[seg * 4 + cb].y;
      b.u[2] = bfr[seg * 4 + cb].z;
      b.u[3] = bfr[seg * 4 + cb].w;
      acc[cb] = __builtin_amdgcn_mfma_f32_16x16x32_bf16(a.v, b.v, acc[cb], 0, 0, 0);
    }
  }

  // ---- epilogue: sin/cos + store. C/D: row (=point) = (l>>4)*4+reg, col = l&15 ----
  int jc = l & 15;
#pragma unroll
  for (int cb = 0; cb < 4; ++cb) {
#pragma unroll
    for (int reg = 0; reg < 4; ++reg) {
      float v = acc[cb][reg];
      float sv = __builtin_amdgcn_sinf(v);   // reference is sin(2*pi*dot); v_sin takes revolutions
      float cv = __builtin_amdgcn_cosf(v);
      float* po = out + (size_t)rowr[reg] * 128 + cb * 16 + jc;
      po[0] = sv;
      po[64] = cv;
    }
  }
}

// ---------------- launcher ----------------

extern "C" void kernel_launch(void* const* d_in, const int* in_sizes, int n_in,
                              void* d_out, int out_size, void* d_ws, size_t ws_size,
                              hipStream_t stream) {
  const float* coords = (const float*)d_in[0];
  const float* plane3 = (const float*)d_in[1];
  const float* plane2 = (const float*)d_in[2];
  const float* vec1   = (const float*)d_in[3];
  const float* B      = (const float*)d_in[4];
  float* out = (float*)d_out;
  int N = in_sizes[0] / 3;

  char* ws = (char*)d_ws;
  size_t off = 0;
  auto take = [&](size_t bytes) { size_t o = off; off = (off + bytes + 4095) & ~(size_t)4095; return o; };
  const size_t off_p3 = take((size_t)3 * PL3);
  const size_t off_p2 = take((size_t)3 * PL2);
  const size_t off_vt = take((size_t)3 * PLV);
  const size_t off_bf = take(768 * 16);
  const size_t off_hist = take(NBINS * 4);
  const size_t off_offs = take(NBINS * 4);
  const size_t off_sorted = take((size_t)N * 16);
  uint8_t* p3t = (uint8_t*)(ws + off_p3);
  uint8_t* p2t = (uint8_t*)(ws + off_p2);
  uint8_t* vt  = (uint8_t*)(ws + off_vt);
  uint4* Bf = (uint4*)(ws + off_bf);
  uint32_t* hist = (uint32_t*)(ws + off_hist);
  uint32_t* offs = (uint32_t*)(ws + off_offs);
  float4* sorted = (float4*)(ws + off_sorted);

  hipLaunchKernelGGL(prep_all, dim3(PREP_BLOCKS), dim3(256), 0, stream,
                     B, Bf, hist, plane3, p3t, plane2, p2t, vec1, vt);
  hipLaunchKernelGGL(hist_kernel, dim3((N + 255) / 256), dim3(256), 0, stream, coords, hist, N);
  hipLaunchKernelGGL(scan_kernel, dim3(1), dim3(1024), 0, stream, hist, offs);
  hipLaunchKernelGGL(scatter_kernel, dim3((N + 255) / 256), dim3(256), 0, stream, coords, offs, sorted, N);
  hipLaunchKernelGGL(triplane_main, dim3((N * 4 + 255) / 256), dim3(256), 0, stream,
                     sorted, p3t, p2t, vt, Bf, out, N);
}

// Round 11
// 182.151 us; speedup vs baseline: 1.5582x; 1.0234x over previous
//
#include <hip/hip_runtime.h>
#include <hip/hip_bf16.h>
#include <stdint.h>

typedef float f32x2 __attribute__((ext_vector_type(2)));
typedef float f32x4 __attribute__((ext_vector_type(4)));
typedef short s16x8 __attribute__((ext_vector_type(8)));

#define CUBIC_A (-0.75f)
#define S3 262144.0f   // 2^18 scale for plane3
#define S2 131072.0f   // 2^17 scale for plane2
#define SV 32768.0f    // 2^15 scale for vec

// padded plane geometry (x-axis padded with clamped border texels at both ends)
#define PL3 (128 * 132 * 32)   // per-plane bytes, scale 3 (H=128, Wp=132)
#define PL2 (256 * 260 * 32)   // scale 2 (H=256, Wp=260)
#define PLV (516 * 32)         // vec (Wp=516)
#define STRIDE3 (132 * 32)
#define STRIDE2 (260 * 32)

#define NBINS 32768            // 5 bits per axis

__device__ __forceinline__ void cubic_w(float t, float* w) {
  float s = t + 1.0f;
  w[0] = ((CUBIC_A * s - 5.0f * CUBIC_A) * s + 8.0f * CUBIC_A) * s - 4.0f * CUBIC_A;
  w[1] = ((CUBIC_A + 2.0f) * t - (CUBIC_A + 3.0f)) * t * t + 1.0f;
  float u = 1.0f - t;
  w[2] = ((CUBIC_A + 2.0f) * u - (CUBIC_A + 3.0f)) * u * u + 1.0f;
  float v = 2.0f - t;
  w[3] = ((CUBIC_A * v - 5.0f * CUBIC_A) * v + 8.0f * CUBIC_A) * v - 4.0f * CUBIC_A;
}

// col-axis: weights + window base byte (padded layout: window start x0-1 -> byte x0*32)
__device__ __forceinline__ void axis_w(float c, int size, float* w, int* colb) {
  float ix = (c + 1.0f) * 0.5f * (float)(size - 1);
  float x0f = floorf(ix);
  cubic_w(ix - x0f, w);
  *colb = (int)x0f * 32;
}

// row-axis: weights + clamped row byte offsets
__device__ __forceinline__ void axis_r(float c, int size, int strideB, float* w, int* ro) {
  float ix = (c + 1.0f) * 0.5f * (float)(size - 1);
  float x0f = floorf(ix);
  cubic_w(ix - x0f, w);
  int x0 = (int)x0f;
#pragma unroll
  for (int k = 0; k < 4; ++k) {
    int qq = x0 - 1 + k;
    qq = qq < 0 ? 0 : qq;
    qq = qq > size - 1 ? size - 1 : qq;
    ro[k] = qq * strideB;
  }
}

// both (y axis is used as rows and cols)
__device__ __forceinline__ void axis_wr(float c, int size, int strideB, float* w, int* colb, int* ro) {
  float ix = (c + 1.0f) * 0.5f * (float)(size - 1);
  float x0f = floorf(ix);
  cubic_w(ix - x0f, w);
  int x0 = (int)x0f;
  *colb = x0 * 32;
#pragma unroll
  for (int k = 0; k < 4; ++k) {
    int qq = x0 - 1 + k;
    qq = qq < 0 ? 0 : qq;
    qq = qq > size - 1 ? size - 1 : qq;
    ro[k] = qq * strideB;
  }
}

// issue 8 x 16B loads: 4 rows x 2 half-windows (lane's q*16 already folded into base)
__device__ __forceinline__ void issueW(const uint8_t* __restrict__ base,
                                       const int* ro, int cb, uint4* r) {
#pragma unroll
  for (int i = 0; i < 4; ++i) {
    r[2 * i]     = *reinterpret_cast<const uint4*>(base + ro[i] + cb);
    r[2 * i + 1] = *reinterpret_cast<const uint4*>(base + ro[i] + cb + 64);
  }
}

// unpack 16 fp8 channels with one weight into acc8 (8 f32x2 = 16 ch)
__device__ __forceinline__ void consume16(uint4 v, float w, f32x2* acc8) {
  f32x2 w2; w2.x = w; w2.y = w;
  acc8[0] += w2 * __builtin_amdgcn_cvt_pk_f32_fp8((int)v.x, false);
  acc8[1] += w2 * __builtin_amdgcn_cvt_pk_f32_fp8((int)v.x, true);
  acc8[2] += w2 * __builtin_amdgcn_cvt_pk_f32_fp8((int)v.y, false);
  acc8[3] += w2 * __builtin_amdgcn_cvt_pk_f32_fp8((int)v.y, true);
  acc8[4] += w2 * __builtin_amdgcn_cvt_pk_f32_fp8((int)v.z, false);
  acc8[5] += w2 * __builtin_amdgcn_cvt_pk_f32_fp8((int)v.z, true);
  acc8[6] += w2 * __builtin_amdgcn_cvt_pk_f32_fp8((int)v.w, false);
  acc8[7] += w2 * __builtin_amdgcn_cvt_pk_f32_fp8((int)v.w, true);
}

// consume one plane sample: 4 rows x {texel p0 (w=wr*cw0), texel p0+2 (w=wr*cw1)}
__device__ __forceinline__ void consumeW(const float* wr, float cw0, float cw1,
                                         const uint4* r, f32x2* acc8) {
#pragma unroll
  for (int i = 0; i < 4; ++i) {
    consume16(r[2 * i],     wr[i] * cw0, acc8);
    consume16(r[2 * i + 1], wr[i] * cw1, acc8);
  }
}

// ---------------- sort helpers ----------------

__device__ __forceinline__ int bin_of(float x, float y, float z) {
  int bx = (int)((x + 1.0f) * 16.0f); bx = bx < 0 ? 0 : (bx > 31 ? 31 : bx);
  int by = (int)((y + 1.0f) * 16.0f); by = by < 0 ? 0 : (by > 31 ? 31 : by);
  int bz = (int)((z + 1.0f) * 16.0f); bz = bz < 0 ? 0 : (bz > 31 ? 31 : bz);
  return (bz << 10) | (by << 5) | bx;   // x fastest
}

// ---------------- fused prep device functions ----------------

__device__ __forceinline__ float comb_row(const float* __restrict__ B, int r, int j) {
  return (r < 32) ? (B[r * 64 + j] + B[(r + 32) * 64 + j]) : B[(r + 32) * 64 + j];
}

__device__ __forceinline__ uint32_t pack_bf16(float v0, float v1) {
  uint32_t a = __float_as_uint(v0);
  uint32_t b = __float_as_uint(v1);
  uint32_t r0 = (a + 0x7fffu + ((a >> 16) & 1u)) >> 16;     // RNE
  uint32_t r1 = (b + 0x7fffu + ((b >> 16) & 1u)) >> 16;
  return (r0 & 0xffffu) | (r1 << 16);
}

__device__ __forceinline__ void bfrag_body(int i, const float* __restrict__ B, uint4* __restrict__ Bf) {
  if (i >= 768) return;
  int lane = i & 63;
  int cb = (i >> 6) & 3;
  int seg = i >> 8;
  float invS = (seg == 0) ? (1.0f / S3) : (seg == 1) ? (1.0f / S2) : (1.0f / SV);
  int j = cb * 16 + (lane & 15);
  int h = lane >> 4;
  uint32_t o[4];
#pragma unroll
  for (int r = 0; r < 4; ++r) {
    int k0 = seg * 32 + h * 8 + 2 * r;
    float v0 = comb_row(B, k0, j) * invS;
    float v1 = comb_row(B, k0 + 1, j) * invS;
    o[r] = pack_bf16(v0, v1);
  }
  uint4 st; st.x = o[0]; st.y = o[1]; st.z = o[2]; st.w = o[3];
  Bf[(seg * 4 + cb) * 64 + lane] = st;
}

// Transpose+quantize (P, 32, H, W) fp32 -> (P, H, Wp, 32) fp8 e4m3 scaled by S,
// with x-padding: texel x stored at slot x+1; slot 0 = texel 0; slots W+1,W+2 = texel W-1.
__device__ __forceinline__ void transpose_body(int b, const float* __restrict__ in,
                                               uint8_t* __restrict__ out,
                                               int H, int W, int Wp, int nxt, float S) {
  __shared__ float tile[32][65];
  int xt = b % nxt;
  int tmp = b / nxt;
  int y = tmp % H;
  int p = tmp / H;
  int x0 = xt * 64;
  int lane = threadIdx.x;
  const float* src = in + ((size_t)p * 32 * (size_t)H) * (size_t)W + (size_t)y * (size_t)W;
  int cx = lane & 63;
  int c4 = lane >> 6;
#pragma unroll
  for (int pass = 0; pass < 8; ++pass) {
    int c = pass * 4 + c4;
    tile[c][cx] = src[(size_t)c * (size_t)(H) * (size_t)W + x0 + cx];
  }
  __syncthreads();
  int xx = lane >> 2;
  int c8 = (lane & 3) * 8;
  float f[8];
#pragma unroll
  for (int i = 0; i < 8; ++i) f[i] = tile[c8 + i][xx] * S;
  uint32_t lo = 0, hi = 0;
  lo = (uint32_t)__builtin_amdgcn_cvt_pk_fp8_f32(f[0], f[1], (int)lo, false);
  lo = (uint32_t)__builtin_amdgcn_cvt_pk_fp8_f32(f[2], f[3], (int)lo, true);
  hi = (uint32_t)__builtin_amdgcn_cvt_pk_fp8_f32(f[4], f[5], (int)hi, false);
  hi = (uint32_t)__builtin_amdgcn_cvt_pk_fp8_f32(f[6], f[7], (int)hi, true);
  uint2 st; st.x = lo; st.y = hi;
  int x = x0 + xx;
  uint8_t* rowb = out + (((size_t)p * H + y) * (size_t)Wp) * 32;
  *reinterpret_cast<uint2*>(rowb + (size_t)(x + 1) * 32 + c8) = st;
  if (x == 0)
    *reinterpret_cast<uint2*>(rowb + c8) = st;
  if (x == W - 1) {
    *reinterpret_cast<uint2*>(rowb + (size_t)(W + 1) * 32 + c8) = st;
    *reinterpret_cast<uint2*>(rowb + (size_t)(W + 2) * 32 + c8) = st;
  }
}

// fused prep: [0,3) bfrag | [3,131) zero hist | [131,899) p3 | [899,3971) p2 | [3971,3995) vec
#define PREP_BLOCKS 3995
__global__ void __launch_bounds__(256) prep_all(const float* __restrict__ B, uint4* __restrict__ Bf,
                                                uint32_t* __restrict__ hist,
                                                const float* __restrict__ plane3, uint8_t* __restrict__ p3t,
                                                const float* __restrict__ plane2, uint8_t* __restrict__ p2t,
                                                const float* __restrict__ vec1, uint8_t* __restrict__ vt) {
  int bid = blockIdx.x;
  if (bid < 3) {
    bfrag_body(bid * 256 + threadIdx.x, B, Bf);
  } else if (bid < 131) {
    int i = (bid - 3) * 256 + threadIdx.x;
    if (i < NBINS) hist[i] = 0;
  } else if (bid < 899) {
    transpose_body(bid - 131, plane3, p3t, 128, 128, 132, 2, S3);
  } else if (bid < 3971) {
    transpose_body(bid - 899, plane2, p2t, 256, 256, 260, 4, S2);
  } else {
    transpose_body(bid - 3971, vec1, vt, 1, 512, 516, 8, SV);
  }
}

// ---------------- sort kernels ----------------

__global__ void __launch_bounds__(256) hist_kernel(const float* __restrict__ coords,
                                                   uint32_t* __restrict__ hist, int N) {
  int i = blockIdx.x * 256 + threadIdx.x;
  if (i >= N) return;
  int b = bin_of(coords[3 * i], coords[3 * i + 1], coords[3 * i + 2]);
  atomicAdd(&hist[b], 1u);
}

// one block of 1024 threads; each owns 32 consecutive bins
__global__ void __launch_bounds__(1024) scan_kernel(const uint32_t* __restrict__ hist,
                                                    uint32_t* __restrict__ offs) {
  __shared__ uint32_t s[1024];
  int t = threadIdx.x;
  uint32_t sum = 0;
#pragma unroll
  for (int k = 0; k < 32; ++k) sum += hist[t * 32 + k];
  s[t] = sum;
  __syncthreads();
  for (int d = 1; d < 1024; d <<= 1) {
    uint32_t v = (t >= d) ? s[t - d] : 0;
    __syncthreads();
    s[t] += v;
    __syncthreads();
  }
  uint32_t run = (t == 0) ? 0 : s[t - 1];
#pragma unroll
  for (int k = 0; k < 32; ++k) {
    offs[t * 32 + k] = run;
    run += hist[t * 32 + k];
  }
}

__global__ void __launch_bounds__(256) scatter_kernel(const float* __restrict__ coords,
                                                      uint32_t* __restrict__ offs,
                                                      float4* __restrict__ sorted, int N) {
  int i = blockIdx.x * 256 + threadIdx.x;
  if (i >= N) return;
  float x = coords[3 * i], y = coords[3 * i + 1], z = coords[3 * i + 2];
  int b = bin_of(x, y, z);
  uint32_t pos = atomicAdd(&offs[b], 1u);
  float4 v; v.x = x; v.y = y; v.z = z; v.w = __int_as_float(i);
  sorted[pos] = v;
}

// ---------------- main kernel: sorted window gathers, MFMA projection ----------------

__global__ void __launch_bounds__(256, 6) triplane_main(
    const float4* __restrict__ sorted, // (N) x (x,y,z,idx)
    const uint8_t* __restrict__ p3t,   // (3,128,132,32) fp8, x-padded
    const uint8_t* __restrict__ p2t,   // (3,256,260,32) fp8
    const uint8_t* __restrict__ vt,    // (3,516,32) fp8
    const uint4* __restrict__ Bfrag,   // [3][4][64] uint4
    float* __restrict__ out, int N) {
  // per-wave private LDS slice for epilogue transpose: 8 rows x 132 floats
  __shared__ float ep_lds[4][8 * 132];
  int t = blockIdx.x * 256 + threadIdx.x;
  int l = threadIdx.x & 63;
  int n0 = (blockIdx.x * 256 + (threadIdx.x & ~63)) >> 2;  // first point of this wave
  if (n0 >= N) return;
  int n = t >> 2;
  int q = l & 3;
  bool hiq = (q >> 1) != 0;   // texel-pair selector
  int q16 = q * 16;

  float4 pd = sorted[n];
  float x = pd.x;
  float y = pd.y;
  float z = pd.z;
  int oidx = __float_as_int(pd.w);

  f32x2 feat2[24];   // [seg=3][8]: entry e = channels {2e,2e+1} of this lane's 16-ch half
#pragma unroll
  for (int i = 0; i < 24; ++i) { feat2[i].x = 0.f; feat2[i].y = 0.f; }

  uint4 rA[8], rB[8];

  // ======== scale 3 (H=128) ========
  float wx[4], wy[4], wz[4];
  int cbx, cby, roy[4], roz[4];
  axis_w(x, 128, wx, &cbx);
  axis_wr(y, 128, STRIDE3, wy, &cby, roy);
  axis_r(z, 128, STRIDE3, wz, roz);
  float cx0 = hiq ? wx[1] : wx[0], cx1 = hiq ? wx[3] : wx[2];
  float cy0 = hiq ? wy[1] : wy[0], cy1 = hiq ? wy[3] : wy[2];

  const uint8_t* b3 = p3t + q16;
  issueW(b3,           roy, cbx, rA);   // xy: rows y, cols x
  issueW(b3 + 1 * PL3, roz, cby, rB);   // yz: rows z, cols y
  consumeW(wy, cx0, cx1, rA, feat2 + 0);
  issueW(b3 + 2 * PL3, roz, cbx, rA);   // xz: rows z, cols x
  consumeW(wz, cy0, cy1, rB, feat2 + 0);

  // ======== scale 2 (H=256) ========
  float wx2[4], wy2[4], wz2[4];
  int cbx2, cby2, roy2[4], roz2[4];
  axis_w(x, 256, wx2, &cbx2);
  axis_wr(y, 256, STRIDE2, wy2, &cby2, roy2);
  axis_r(z, 256, STRIDE2, wz2, roz2);
  float cx20 = hiq ? wx2[1] : wx2[0], cx21 = hiq ? wx2[3] : wx2[2];
  float cy20 = hiq ? wy2[1] : wy2[0], cy21 = hiq ? wy2[3] : wy2[2];

  const uint8_t* b2 = p2t + q16;
  issueW(b2,           roy2, cbx2, rB);               // p2 xy
  consumeW(wz, cx0, cx1, rA, feat2 + 0);              // p3 xz
  issueW(b2 + 1 * PL2, roz2, cby2, rA);               // p2 yz
  consumeW(wy2, cx20, cx21, rB, feat2 + 8);           // p2 xy
  issueW(b2 + 2 * PL2, roz2, cbx2, rB);               // p2 xz
  consumeW(wz2, cy20, cy21, rA, feat2 + 8);           // p2 yz

  // ======== vector (W=512) ========
  float wvx[4], wvy[4], wvz[4];
  int cbvx, cbvy, cbvz;
  axis_w(x, 512, wvx, &cbvx);
  axis_w(y, 512, wvy, &cbvy);
  axis_w(z, 512, wvz, &cbvz);
  {
    const uint8_t* v0 = vt + q16;
    rA[0] = *reinterpret_cast<const uint4*>(v0 + cbvx);
    rA[1] = *reinterpret_cast<const uint4*>(v0 + cbvx + 64);
    rA[2] = *reinterpret_cast<const uint4*>(v0 + PLV + cbvy);
    rA[3] = *reinterpret_cast<const uint4*>(v0 + PLV + cbvy + 64);
    rA[4] = *reinterpret_cast<const uint4*>(v0 + 2 * PLV + cbvz);
    rA[5] = *reinterpret_cast<const uint4*>(v0 + 2 * PLV + cbvz + 64);
  }
  consumeW(wz2, cx20, cx21, rB, feat2 + 8);           // p2 xz
  {
    float a0 = hiq ? wvx[1] : wvx[0], a1 = hiq ? wvx[3] : wvx[2];
    float b0 = hiq ? wvy[1] : wvy[0], b1 = hiq ? wvy[3] : wvy[2];
    float c0 = hiq ? wvz[1] : wvz[0], c1 = hiq ? wvz[3] : wvz[2];
    consume16(rA[0], a0, feat2 + 16);
    consume16(rA[1], a1, feat2 + 16);
    consume16(rA[2], b0, feat2 + 16);
    consume16(rA[3], b1, feat2 + 16);
    consume16(rA[4], c0, feat2 + 16);
    consume16(rA[5], c1, feat2 + 16);
  }

  // ---- pair-reduce (lane q with lane q^2) + pack own k-quarter to bf16 ----
  // lane q owns quarter qq = ((q&1)<<1)|(q>>1): half q&1, channel offset 8*(q>>1)
  uint32_t packed[12];
#pragma unroll
  for (int s = 0; s < 3; ++s) {
#pragma unroll
    for (int r = 0; r < 4; ++r) {
      f32x2 lo = feat2[s * 8 + r];
      f32x2 hi = feat2[s * 8 + 4 + r];
      float ownx = hiq ? hi.x : lo.x, owny = hiq ? hi.y : lo.y;
      float sndx = hiq ? lo.x : hi.x, sndy = hiq ? lo.y : hi.y;
      float rx = ownx + __shfl_xor(sndx, 2);
      float ry = owny + __shfl_xor(sndy, 2);
      uint32_t pk;
      asm("v_cvt_pk_bf16_f32 %0, %1, %2" : "=v"(pk) : "v"(rx), "v"(ry));
      packed[s * 4 + r] = pk;
    }
  }

  // ---- redistribute to MFMA A-fragment: dest lane 16h'+p pulls quarter h' of point p.
  // quarter h' lives in lane 4p + ((h'&1)<<1 | h'>>1)
  int hp = l >> 4;
  int srcq = ((hp & 1) << 1) | (hp >> 1);
  int baddr = (4 * (l & 15) + srcq) * 4;
  uint32_t apk[12];
#pragma unroll
  for (int i = 0; i < 12; ++i)
    apk[i] = (uint32_t)__builtin_amdgcn_ds_bpermute(baddr, (int)packed[i]);

  // ---- load B fragments ----
  uint4 bfr[12];
#pragma unroll
  for (int i = 0; i < 12; ++i) bfr[i] = Bfrag[i * 64 + l];

  // ---- 12 MFMAs ----
  union U { uint32_t u[4]; s16x8 v; };
  f32x4 acc[4];
#pragma unroll
  for (int cb = 0; cb < 4; ++cb) { acc[cb].x = 0.f; acc[cb].y = 0.f; acc[cb].z = 0.f; acc[cb].w = 0.f; }
#pragma unroll
  for (int seg = 0; seg < 3; ++seg) {
    U a;
    a.u[0] = apk[seg * 4 + 0];
    a.u[1] = apk[seg * 4 + 1];
    a.u[2] = apk[seg * 4 + 2];
    a.u[3] = apk[seg * 4 + 3];
#pragma unroll
    for (int cb = 0; cb < 4; ++cb) {
      U b;
      b.u[0] = bfr[seg * 4 + cb].x;
      b.u[1] = bfr[seg * 4 + cb].y;
      b.u[2] = bfr[seg * 4 + cb].z;
      b.u[3] = bfr[seg * 4 + cb].w;
      acc[cb] = __builtin_amdgcn_mfma_f32_16x16x32_bf16(a.v, b.v, acc[cb], 0, 0, 0);
    }
  }

  // ---- epilogue: sin/cos -> per-wave LDS transpose -> dwordx4 stores ----
  // C/D: point p_w = 4*hp + reg, col = cb*16 + jc (sin) / +64 (cos)
  float* wl = ep_lds[threadIdx.x >> 6];
  int jc = l & 15;
  int r_l = l >> 3;        // LDS row this lane reads (0..7)
  int ck = l & 7;          // chunk-in-row selector
#pragma unroll
  for (int pass = 0; pass < 2; ++pass) {
    // write 8 rows (reg = 2*pass + rr), LDS row = 2*hp + rr, stride 132 (2-way bank alias = free)
#pragma unroll
    for (int rr = 0; rr < 2; ++rr) {
      int reg = 2 * pass + rr;
      float* base = wl + (2 * hp + rr) * 132 + jc;
#pragma unroll
      for (int cb = 0; cb < 4; ++cb) {
        float v = acc[cb][reg];
        base[cb * 16]      = __builtin_amdgcn_sinf(v);  // ref: sin(2*pi*dot); v_sin takes revolutions
        base[cb * 16 + 64] = __builtin_amdgcn_cosf(v);
      }
    }
    // read back as contiguous row chunks + coalesced dwordx4 stores
    // (same-wave DS ops are in-order; slices are per-wave private -> no barrier)
    int p_w = 4 * (r_l >> 1) + (r_l & 1) + 2 * pass;
    int rowg = __shfl(oidx, p_w * 4);
    const float* rbase = wl + r_l * 132 + 4 * ck;
    float* gbase = out + (size_t)rowg * 128 + 4 * ck;
#pragma unroll
    for (int k = 0; k < 4; ++k) {
      float4 vv = *reinterpret_cast<const float4*>(rbase + 32 * k);
      *reinterpret_cast<float4*>(gbase + 32 * k) = vv;
    }
  }
}

// ---------------- launcher ----------------

extern "C" void kernel_launch(void* const* d_in, const int* in_sizes, int n_in,
                              void* d_out, int out_size, void* d_ws, size_t ws_size,
                              hipStream_t stream) {
  const float* coords = (const float*)d_in[0];
  const float* plane3 = (const float*)d_in[1];
  const float* plane2 = (const float*)d_in[2];
  const float* vec1   = (const float*)d_in[3];
  const float* B      = (const float*)d_in[4];
  float* out = (float*)d_out;
  int N = in_sizes[0] / 3;

  char* ws = (char*)d_ws;
  size_t off = 0;
  auto take = [&](size_t bytes) { size_t o = off; off = (off + bytes + 4095) & ~(size_t)4095; return o; };
  const size_t off_p3 = take((size_t)3 * PL3);
  const size_t off_p2 = take((size_t)3 * PL2);
  const size_t off_vt = take((size_t)3 * PLV);
  const size_t off_bf = take(768 * 16);
  const size_t off_hist = take(NBINS * 4);
  const size_t off_offs = take(NBINS * 4);
  const size_t off_sorted = take((size_t)N * 16);
  uint8_t* p3t = (uint8_t*)(ws + off_p3);
  uint8_t* p2t = (uint8_t*)(ws + off_p2);
  uint8_t* vt  = (uint8_t*)(ws + off_vt);
  uint4* Bf = (uint4*)(ws + off_bf);
  uint32_t* hist = (uint32_t*)(ws + off_hist);
  uint32_t* offs = (uint32_t*)(ws + off_offs);
  float4* sorted = (float4*)(ws + off_sorted);

  hipLaunchKernelGGL(prep_all, dim3(PREP_BLOCKS), dim3(256), 0, stream,
                     B, Bf, hist, plane3, p3t, plane2, p2t, vec1, vt);
  hipLaunchKernelGGL(hist_kernel, dim3((N + 255) / 256), dim3(256), 0, stream, coords, hist, N);
  hipLaunchKernelGGL(scan_kernel, dim3(1), dim3(1024), 0, stream, hist, offs);
  hipLaunchKernelGGL(scatter_kernel, dim3((N + 255) / 256), dim3(256), 0, stream, coords, offs, sorted, N);
  hipLaunchKernelGGL(triplane_main, dim3((N * 4 + 255) / 256), dim3(256), 0, stream,
                     sorted, p3t, p2t, vt, Bf, out, N);
}